// Round 13
// baseline (375.771 us; speedup 1.0000x reference)
//
#include <hip/hip_runtime.h>
#include <math.h>

#define N_NODES_C 50000
#define E_C       800000
#define ATT_IN_C  176
#define ATT_HID_C 144
#define SCAN_B    98      // ceil(50000 / 512)
#define UPD_TILES 3125    // 50000 / 16 exact
#define DEG_B     3125    // 800000 / 256 exact
#define CVT_B     1978    // ceil(506240 / 256)
#define SCORE_B   256     // 1 wave/SIMD: the ONLY non-spill regime (r0-r12 ledger)

typedef __attribute__((ext_vector_type(8))) __bf16 bf16x8;
typedef __attribute__((ext_vector_type(4))) float f32x4;

// ---- workspace layout (bytes). HIGH-WATER 43,903,488 B (< proven 55.1MB).
#define O_RAW   0L          // float[E] 3.2MB
#define O_DEG   3200000L    // int[N]
#define O_OFF   3400704L    // int[N+1]
#define O_CUR   3601408L    // int[N]
#define O_CSR   3802112L    // uint[E]  packed src|dst<<16 (ids < 2^16)
#define O_EFC   7002112L    // bf16[E*16]  CSR-ordered edge features
#define O_XB    32602112L   // bf16[N*64]
#define O_XSB   39002112L   // bf16[N*16]
#define O_W1B   40602112L   // bf16[144*176]
#define O_UW1B  40653312L   // bf16[128*128]
#define O_UW2B  40686080L   // bf16[64*128]
#define O_PSUM  40702464L   // int[98] (scan1->scan3 only)
#define O_PERM  40703488L   // int[E] 3.2MB (k_fill->k_fill2 only; old aggb region)

__device__ __forceinline__ bf16x8 bzero8() {
    bf16x8 z;
#pragma unroll
    for (int i = 0; i < 8; ++i) z[i] = (__bf16)0.0f;
    return z;
}

// ---- fused: degree count (blocks 0..DEG_B) + fp32->bf16 convert (no ef)
__global__ __launch_bounds__(256) void k_prep(
    const int* __restrict__ ei,
    const float* __restrict__ x, const float* __restrict__ xs,
    const float* __restrict__ w1,
    const float* __restrict__ uw1, const float* __restrict__ uw2,
    int* __restrict__ deg,
    __bf16* __restrict__ xb, __bf16* __restrict__ xsb,
    __bf16* __restrict__ w1b,
    __bf16* __restrict__ uw1b, __bf16* __restrict__ uw2b)
{
    int bid = blockIdx.x;
    if (bid < DEG_B) {
        int e = bid * 256 + threadIdx.x;
        if (e < E_C) atomicAdd(&deg[ei[E_C + e]], 1);
        return;
    }
    long g = (long)(bid - DEG_B) * 256 + threadIdx.x;  // one group = 8 floats
    const long G_X = 400000, G_XS = 500000, G_W1 = 503168,
               G_UW1 = 505216, G_UW2 = 506240;
    if (g >= G_UW2) return;
    const float* src; __bf16* dst; long off;
    if (g < G_X)        { src = x;   dst = xb;   off = g * 8; }
    else if (g < G_XS)  { src = xs;  dst = xsb;  off = (g - G_X) * 8; }
    else if (g < G_W1)  { src = w1;  dst = w1b;  off = (g - G_XS) * 8; }
    else if (g < G_UW1) { src = uw1; dst = uw1b; off = (g - G_W1) * 8; }
    else                { src = uw2; dst = uw2b; off = (g - G_UW1) * 8; }
    float4 a = *(const float4*)(src + off);
    float4 b = *(const float4*)(src + off + 4);
    bf16x8 o;
    o[0] = (__bf16)a.x; o[1] = (__bf16)a.y; o[2] = (__bf16)a.z; o[3] = (__bf16)a.w;
    o[4] = (__bf16)b.x; o[5] = (__bf16)b.y; o[6] = (__bf16)b.z; o[7] = (__bf16)b.w;
    *(bf16x8*)(dst + off) = o;
}

// ---- scan phase 1: per-512-node partial sums
__global__ __launch_bounds__(256) void k_scan1(const int* __restrict__ deg,
                                               int* __restrict__ psum) {
    __shared__ int red[256];
    int b = blockIdx.x, t = threadIdx.x;
    int i = b * 512 + t * 2;
    int s = 0;
    if (i < N_NODES_C) s += deg[i];
    if (i + 1 < N_NODES_C) s += deg[i + 1];
    red[t] = s;
    __syncthreads();
#pragma unroll
    for (int off = 128; off > 0; off >>= 1) {
        if (t < off) red[t] += red[t + off];
        __syncthreads();
    }
    if (t == 0) psum[b] = red[0];
}

// ---- scan phase 2+3 fused
__global__ __launch_bounds__(256) void k_scan3(const int* __restrict__ deg,
                                               const int* __restrict__ psum,
                                               int* __restrict__ offsets,
                                               int* __restrict__ cursor) {
    __shared__ int sc[256];
    __shared__ int bo[2];
    int b = blockIdx.x, t = threadIdx.x;
    if (t < 64) {
        int v1 = (t < SCAN_B) ? psum[t] : 0;
        int v2 = (t + 64 < SCAN_B) ? psum[t + 64] : 0;
        int c   = ((t < b) ? v1 : 0) + ((t + 64 < b) ? v2 : 0);
        int tot = v1 + v2;
#pragma unroll
        for (int off = 32; off > 0; off >>= 1) {
            c   += __shfl_xor(c, off, 64);
            tot += __shfl_xor(tot, off, 64);
        }
        if (t == 0) { bo[0] = c; bo[1] = tot; }
    }
    int i = b * 512 + t * 2;
    int d0 = (i < N_NODES_C) ? deg[i] : 0;
    int d1 = (i + 1 < N_NODES_C) ? deg[i + 1] : 0;
    int s = d0 + d1;
    sc[t] = s;
    __syncthreads();
#pragma unroll
    for (int off = 1; off < 256; off <<= 1) {
        int val = sc[t];
        int add = (t >= off) ? sc[t - off] : 0;
        __syncthreads();
        sc[t] = val + add;
        __syncthreads();
    }
    int excl = bo[0] + sc[t] - s;
    if (i < N_NODES_C)     { offsets[i]     = excl;      cursor[i]     = excl; }
    if (i + 1 < N_NODES_C) { offsets[i + 1] = excl + d0; cursor[i + 1] = excl + d0; }
    if (b == 0 && t == 0)  offsets[N_NODES_C] = bo[1];
}

// ---- CSR fill phase A: slot assignment only (two 4B scatters). The 32B ef
// scatter that used to live here (random RMW writes) moves to k_fill2 as
// coalesced writes + random READS — the memory system's cheap direction.
__global__ __launch_bounds__(256) void k_fill(const int* __restrict__ ei,
                                              int* __restrict__ cursor,
                                              unsigned* __restrict__ csrp,
                                              int* __restrict__ perm) {
    int e = blockIdx.x * blockDim.x + threadIdx.x;
    if (e < E_C) {
        int src  = ei[e];
        int dst  = ei[E_C + e];
        int slot = atomicAdd(&cursor[dst], 1);
        csrp[slot] = (unsigned)src | ((unsigned)dst << 16);
        perm[slot] = e;
    }
}

// ---- CSR fill phase B: slot-coalesced ef permute+convert.
// perm read coalesced; ef row = one random 64B read; efc write coalesced.
__global__ __launch_bounds__(256) void k_fill2(const int* __restrict__ perm,
                                               const float* __restrict__ ef,
                                               __bf16* __restrict__ efc) {
    int s = blockIdx.x * blockDim.x + threadIdx.x;
    if (s < E_C) {
        long e = perm[s];
        const float4* efp = (const float4*)(ef + e * 16);
        float4 f0 = efp[0], f1 = efp[1], f2 = efp[2], f3 = efp[3];
        bf16x8 o0, o1;
        o0[0] = (__bf16)f0.x; o0[1] = (__bf16)f0.y; o0[2] = (__bf16)f0.z; o0[3] = (__bf16)f0.w;
        o0[4] = (__bf16)f1.x; o0[5] = (__bf16)f1.y; o0[6] = (__bf16)f1.z; o0[7] = (__bf16)f1.w;
        o1[0] = (__bf16)f2.x; o1[1] = (__bf16)f2.y; o1[2] = (__bf16)f2.z; o1[3] = (__bf16)f2.w;
        o1[4] = (__bf16)f3.x; o1[5] = (__bf16)f3.y; o1[6] = (__bf16)f3.z; o1[7] = (__bf16)f3.w;
        __bf16* d = efc + (long)s * 16;
        *(bf16x8*)d       = o0;
        *(bf16x8*)(d + 8) = o1;
    }
}

// ---- A-fragment gather: full K=176 (x_src|x_dst|xs_src|xs_dst|ef)
__device__ __forceinline__ void load_afrags(
    int src, int dst, long slot, int quad,
    const __bf16* __restrict__ xb, const __bf16* __restrict__ xsb,
    const __bf16* __restrict__ efc,
    bf16x8 a[6])
{
    const __bf16* px = xb + (long)src * 64 + quad * 8;
    const __bf16* pd = xb + (long)dst * 64 + quad * 8;
    a[0] = *(const bf16x8*)(px);
    a[1] = *(const bf16x8*)(px + 32);
    a[2] = *(const bf16x8*)(pd);
    a[3] = *(const bf16x8*)(pd + 32);
    if (quad < 2) {
        a[4] = *(const bf16x8*)(xsb + (long)src * 16 + quad * 8);
        a[5] = *(const bf16x8*)(efc + slot * 16 + quad * 8);
    } else {
        a[4] = *(const bf16x8*)(xsb + (long)dst * 16 + (quad - 2) * 8);
        a[5] = bzero8();
    }
}

// ---- edge attention MLP: r12 CHAMPION, byte-identical. 2-pair ILP,
// 2-slot in-place depth-2 pipeline (copy-free). 72.6us, VGPR 256, no
// spill. Occupancy axis closed (r0-r11); depth-3 needs +48 regs (spill,
// r6). DO NOT add launch_bounds min-waves or touch the loop structure.
__global__ __launch_bounds__(256) void k_scores_mfma(
    const __bf16* __restrict__ xb, const __bf16* __restrict__ xsb,
    const __bf16* __restrict__ efc, const __bf16* __restrict__ w1b,
    const unsigned* __restrict__ csrp,
    const float* __restrict__ b1, const float* __restrict__ w2,
    const float* __restrict__ b2, float* __restrict__ raw)
{
    __shared__ __bf16 w1s[144 * 184];   // 52,992 B
    int tid  = threadIdx.x;
    int lane = tid & 63;

    for (int c = tid; c < 144 * 22; c += 256) {
        int n = c / 22, kk = (c % 22) * 8;
        *(bf16x8*)&w1s[n * 184 + kk] = *(const bf16x8*)(w1b + (long)n * ATT_IN_C + kk);
    }
    for (int n = tid; n < 144; n += 256)
        *(bf16x8*)&w1s[n * 184 + 176] = bzero8();
    __syncthreads();

    int w = blockIdx.x * 4 + (tid >> 6);      // global wave 0..1023
    const int NP = E_C / 32;                  // 25000 edge-pairs
    int per = (NP + 1023) / 1024;             // 25
    long j0 = (long)w * per;
    long j1 = j0 + per; if (j1 > NP) j1 = NP;
    if (j0 >= j1) return;

    int mrow = lane & 15;
    int quad = lane >> 4;
    const __bf16* wls = &w1s[mrow * 184 + quad * 8];

    float b1v[9], w2v[9];
#pragma unroll
    for (int nt = 0; nt < 9; ++nt) {
        int n = nt * 16 + mrow;
        b1v[nt] = b1[n];
        w2v[nt] = w2[n];
    }
    float b2v = b2[0];

    bf16x8 A0[6], B0[6], A1[6], B1[6];
    {
        unsigned e0 = csrp[j0 * 32 + mrow];
        unsigned e1 = csrp[j0 * 32 + 16 + mrow];
        load_afrags((int)(e0 & 0xFFFFu), (int)(e0 >> 16), j0 * 32 + mrow,
                    quad, xb, xsb, efc, A0);
        load_afrags((int)(e1 & 0xFFFFu), (int)(e1 >> 16), j0 * 32 + 16 + mrow,
                    quad, xb, xsb, efc, B0);
        if (j0 + 1 < j1) {
            unsigned f0 = csrp[(j0 + 1) * 32 + mrow];
            unsigned f1 = csrp[(j0 + 1) * 32 + 16 + mrow];
            load_afrags((int)(f0 & 0xFFFFu), (int)(f0 >> 16), (j0 + 1) * 32 + mrow,
                        quad, xb, xsb, efc, A1);
            load_afrags((int)(f1 & 0xFFFFu), (int)(f1 >> 16), (j0 + 1) * 32 + 16 + mrow,
                        quad, xb, xsb, efc, B1);
        }
    }

    auto body = [&](long j, bf16x8 (&FA)[6], bf16x8 (&FB)[6]) {
        unsigned u0 = 0, u1 = 0;
        bool rl = (j + 2 < j1);
        if (rl) {
            u0 = csrp[(j + 2) * 32 + mrow];
            u1 = csrp[(j + 2) * 32 + 16 + mrow];
        }

        f32x4 accA[9], accB[9];
#pragma unroll
        for (int nt = 0; nt < 9; ++nt) {
            accA[nt] = (f32x4){0.f, 0.f, 0.f, 0.f};
            accB[nt] = (f32x4){0.f, 0.f, 0.f, 0.f};
        }
#pragma unroll
        for (int ks = 0; ks < 6; ++ks) {
#pragma unroll
            for (int nt = 0; nt < 9; ++nt) {
                bf16x8 bf = *(const bf16x8*)(wls + nt * (16 * 184) + ks * 32);
                accA[nt] = __builtin_amdgcn_mfma_f32_16x16x32_bf16(
                    FA[ks], bf, accA[nt], 0, 0, 0);
                accB[nt] = __builtin_amdgcn_mfma_f32_16x16x32_bf16(
                    FB[ks], bf, accB[nt], 0, 0, 0);
            }
        }

        if (rl) {
            load_afrags((int)(u0 & 0xFFFFu), (int)(u0 >> 16), (j + 2) * 32 + mrow,
                        quad, xb, xsb, efc, FA);
            load_afrags((int)(u1 & 0xFFFFu), (int)(u1 >> 16), (j + 2) * 32 + 16 + mrow,
                        quad, xb, xsb, efc, FB);
        }

        float pA0 = 0.f, pA1 = 0.f, pA2 = 0.f, pA3 = 0.f;
        float pB0 = 0.f, pB1 = 0.f, pB2 = 0.f, pB3 = 0.f;
#pragma unroll
        for (int nt = 0; nt < 9; ++nt) {
            pA0 += w2v[nt] * fmaxf(accA[nt][0] + b1v[nt], 0.f);
            pA1 += w2v[nt] * fmaxf(accA[nt][1] + b1v[nt], 0.f);
            pA2 += w2v[nt] * fmaxf(accA[nt][2] + b1v[nt], 0.f);
            pA3 += w2v[nt] * fmaxf(accA[nt][3] + b1v[nt], 0.f);
            pB0 += w2v[nt] * fmaxf(accB[nt][0] + b1v[nt], 0.f);
            pB1 += w2v[nt] * fmaxf(accB[nt][1] + b1v[nt], 0.f);
            pB2 += w2v[nt] * fmaxf(accB[nt][2] + b1v[nt], 0.f);
            pB3 += w2v[nt] * fmaxf(accB[nt][3] + b1v[nt], 0.f);
        }
#pragma unroll
        for (int off = 1; off < 16; off <<= 1) {
            pA0 += __shfl_xor(pA0, off, 64);
            pA1 += __shfl_xor(pA1, off, 64);
            pA2 += __shfl_xor(pA2, off, 64);
            pA3 += __shfl_xor(pA3, off, 64);
            pB0 += __shfl_xor(pB0, off, 64);
            pB1 += __shfl_xor(pB1, off, 64);
            pB2 += __shfl_xor(pB2, off, 64);
            pB3 += __shfl_xor(pB3, off, 64);
        }
        if (mrow < 4) {
            float vA = (mrow == 0) ? pA0 : (mrow == 1) ? pA1 : (mrow == 2) ? pA2 : pA3;
            float vB = (mrow == 0) ? pB0 : (mrow == 1) ? pB1 : (mrow == 2) ? pB2 : pB3;
            vA += b2v; vB += b2v;
            vA = (vA >= 0.f) ? vA : 0.01f * vA;
            vB = (vB >= 0.f) ? vB : 0.01f * vB;
            raw[(j * 2) * 16 + quad * 4 + mrow]     = vA;
            raw[(j * 2 + 1) * 16 + quad * 4 + mrow] = vB;
        }
    };

    long j = j0;
    for (; j + 1 < j1; j += 2) {
        body(j,     A0, B0);
        body(j + 1, A1, B1);
    }
    if (j < j1) body(j, A0, B0);
}

// ---- fused segment-softmax aggregate + node update MLP.
// One wave owns one 16-node update tile: aggregates its 16 nodes into
// wave-local LDS (68-elem row stride -> conflict-free ds_read_b128),
// then runs the 2-layer MLP from LDS. Kills the aggb HBM round-trip
// (12.8MB) + one launch. NO __syncthreads (wave-local LDS only; barrier
// would hang on the guard-returned waves of the last block).
__global__ __launch_bounds__(256) void k_aggupd(
    const __bf16* __restrict__ xb, const int* __restrict__ offsets,
    const unsigned* __restrict__ csrp, const float* __restrict__ raw,
    const __bf16* __restrict__ w1b, const float* __restrict__ b1,
    const __bf16* __restrict__ w2b, const float* __restrict__ b2,
    float* __restrict__ out)
{
    __shared__ __bf16 ubuf[4][16 * 136];
    __shared__ __bf16 aggs[4][16 * 68];
    int tid = threadIdx.x, wid = tid >> 6, lane = tid & 63;
    int tile = blockIdx.x * 4 + wid;
    if (tile >= UPD_TILES) return;
    int mrow = lane & 15, quad = lane >> 4;

    // ---- agg phase: this wave's 16 nodes, serially
    __bf16* ag = aggs[wid];
    for (int vl = 0; vl < 16; ++vl) {
        long v = (long)tile * 16 + vl;
        int s0 = offsets[v], s1 = offsets[v + 1];
        float m = -INFINITY;
        for (int p = s0 + lane; p < s1; p += 64) m = fmaxf(m, raw[p]);
#pragma unroll
        for (int off = 32; off > 0; off >>= 1) m = fmaxf(m, __shfl_xor(m, off, 64));
        float acc = 0.f, sum = 0.f;
        int p = s0;
        for (; p + 4 <= s1; p += 4) {
            unsigned c0 = csrp[p], c1 = csrp[p + 1], c2 = csrp[p + 2], c3 = csrp[p + 3];
            float r0 = raw[p], r1 = raw[p + 1], r2 = raw[p + 2], r3 = raw[p + 3];
            float v0 = (float)xb[(long)(c0 & 0xFFFFu) * 64 + lane];
            float v1 = (float)xb[(long)(c1 & 0xFFFFu) * 64 + lane];
            float v2 = (float)xb[(long)(c2 & 0xFFFFu) * 64 + lane];
            float v3 = (float)xb[(long)(c3 & 0xFFFFu) * 64 + lane];
            float w0 = expf(r0 - m), w1 = expf(r1 - m);
            float w2 = expf(r2 - m), w3 = expf(r3 - m);
            sum += (w0 + w1) + (w2 + w3);
            acc += w0 * v0 + w1 * v1 + w2 * v2 + w3 * v3;
        }
        for (; p < s1; ++p) {
            int src = (int)(csrp[p] & 0xFFFFu);
            float wv = expf(raw[p] - m);
            sum += wv;
            acc += wv * (float)xb[(long)src * 64 + lane];
        }
        ag[vl * 68 + lane] = (__bf16)(acc / (sum + 1e-9f));
    }

    // ---- update phase (reads agg from wave-local LDS)
    long node = (long)tile * 16 + mrow;
    bf16x8 a1[4];
    a1[0] = *(const bf16x8*)(xb + node * 64 + quad * 8);
    a1[1] = *(const bf16x8*)(xb + node * 64 + 32 + quad * 8);
    a1[2] = *(const bf16x8*)&ag[mrow * 68 + quad * 8];
    a1[3] = *(const bf16x8*)&ag[mrow * 68 + 32 + quad * 8];

    bf16x8 b1f[4][8];
#pragma unroll
    for (int ks = 0; ks < 4; ++ks)
#pragma unroll
        for (int nt = 0; nt < 8; ++nt)
            b1f[ks][nt] = *(const bf16x8*)(w1b + (long)(nt * 16 + mrow) * 128 + ks * 32 + quad * 8);

    f32x4 acc1[8];
#pragma unroll
    for (int nt = 0; nt < 8; ++nt) acc1[nt] = (f32x4){0.f, 0.f, 0.f, 0.f};
#pragma unroll
    for (int ks = 0; ks < 4; ++ks)
#pragma unroll
        for (int nt = 0; nt < 8; ++nt)
            acc1[nt] = __builtin_amdgcn_mfma_f32_16x16x32_bf16(a1[ks], b1f[ks][nt], acc1[nt], 0, 0, 0);

    __bf16* ub = ubuf[wid];
#pragma unroll
    for (int nt = 0; nt < 8; ++nt) {
        float bb = b1[nt * 16 + mrow];
#pragma unroll
        for (int r = 0; r < 4; ++r) {
            float h = fmaxf(acc1[nt][r] + bb, 0.f);
            ub[(quad * 4 + r) * 136 + nt * 16 + mrow] = (__bf16)h;
        }
    }

    bf16x8 a2[4];
#pragma unroll
    for (int ks = 0; ks < 4; ++ks)
        a2[ks] = *(bf16x8*)&ub[mrow * 136 + ks * 32 + quad * 8];

    bf16x8 b2f[4][4];
#pragma unroll
    for (int ks = 0; ks < 4; ++ks)
#pragma unroll
        for (int nt = 0; nt < 4; ++nt)
            b2f[ks][nt] = *(const bf16x8*)(w2b + (long)(nt * 16 + mrow) * 128 + ks * 32 + quad * 8);

    f32x4 acc2[4];
#pragma unroll
    for (int nt = 0; nt < 4; ++nt) acc2[nt] = (f32x4){0.f, 0.f, 0.f, 0.f};
#pragma unroll
    for (int ks = 0; ks < 4; ++ks)
#pragma unroll
        for (int nt = 0; nt < 4; ++nt)
            acc2[nt] = __builtin_amdgcn_mfma_f32_16x16x32_bf16(a2[ks], b2f[ks][nt], acc2[nt], 0, 0, 0);

#pragma unroll
    for (int nt = 0; nt < 4; ++nt) {
        float bb = b2[nt * 16 + mrow];
#pragma unroll
        for (int r = 0; r < 4; ++r) {
            long nodeo = (long)tile * 16 + quad * 4 + r;
            out[nodeo * 64 + nt * 16 + mrow] = fmaxf(acc2[nt][r] + bb, 0.f);
        }
    }
}

extern "C" void kernel_launch(void* const* d_in, const int* in_sizes, int n_in,
                              void* d_out, int out_size, void* d_ws, size_t ws_size,
                              hipStream_t stream) {
    const float* x    = (const float*)d_in[0];
    const float* xs   = (const float*)d_in[1];
    const int*   ei   = (const int*)d_in[2];
    const float* ef   = (const float*)d_in[3];
    const float* aw1  = (const float*)d_in[4];
    const float* ab1  = (const float*)d_in[5];
    const float* aw2  = (const float*)d_in[6];
    const float* ab2  = (const float*)d_in[7];
    const float* uw1  = (const float*)d_in[8];
    const float* ub1  = (const float*)d_in[9];
    const float* uw2  = (const float*)d_in[10];
    const float* ub2  = (const float*)d_in[11];
    float* out = (float*)d_out;

    char* ws = (char*)d_ws;
    float*     raw     = (float*)(ws + O_RAW);
    int*       deg     = (int*)(ws + O_DEG);
    int*       offsets = (int*)(ws + O_OFF);
    int*       cursor  = (int*)(ws + O_CUR);
    unsigned*  csrp    = (unsigned*)(ws + O_CSR);
    __bf16*    efc     = (__bf16*)(ws + O_EFC);
    __bf16*    xb      = (__bf16*)(ws + O_XB);
    __bf16*    xsb     = (__bf16*)(ws + O_XSB);
    __bf16*    w1b     = (__bf16*)(ws + O_W1B);
    __bf16*    uw1b    = (__bf16*)(ws + O_UW1B);
    __bf16*    uw2b    = (__bf16*)(ws + O_UW2B);
    int*       psum    = (int*)(ws + O_PSUM);
    int*       perm    = (int*)(ws + O_PERM);

    hipMemsetAsync(deg, 0, N_NODES_C * sizeof(int), stream);
    hipLaunchKernelGGL(k_prep,     dim3(DEG_B + CVT_B),           dim3(256), 0, stream,
                       ei, x, xs, aw1, uw1, uw2, deg, xb, xsb, w1b, uw1b, uw2b);
    hipLaunchKernelGGL(k_scan1,    dim3(SCAN_B),                  dim3(256), 0, stream, deg, psum);
    hipLaunchKernelGGL(k_scan3,    dim3(SCAN_B),                  dim3(256), 0, stream,
                       deg, psum, offsets, cursor);
    hipLaunchKernelGGL(k_fill,     dim3((E_C + 255) / 256),       dim3(256), 0, stream,
                       ei, cursor, csrp, perm);
    hipLaunchKernelGGL(k_fill2,    dim3((E_C + 255) / 256),       dim3(256), 0, stream,
                       perm, ef, efc);
    hipLaunchKernelGGL(k_scores_mfma, dim3(SCORE_B),              dim3(256), 0, stream,
                       xb, xsb, efc, w1b, csrp, ab1, aw2, ab2, raw);
    hipLaunchKernelGGL(k_aggupd,   dim3((UPD_TILES + 3) / 4),     dim3(256), 0, stream,
                       xb, offsets, csrp, raw, uw1b, ub1, uw2b, ub2, out);
}

// Round 14
// 349.978 us; speedup vs baseline: 1.0737x; 1.0737x over previous
//
#include <hip/hip_runtime.h>
#include <math.h>

#define N_NODES_C 50000
#define E_C       800000
#define ATT_IN_C  176
#define ATT_HID_C 144
#define SCAN_B    98      // ceil(50000 / 512)
#define UPD_TILES 3125    // 50000 / 16 exact
#define DEG_B     3125    // 800000 / 256 exact
#define CVT_B     1978    // ceil(506240 / 256)
#define SCORE_B   256     // 1 wave/SIMD: the ONLY non-spill regime (r0-r12 ledger)

typedef __attribute__((ext_vector_type(8))) __bf16 bf16x8;
typedef __attribute__((ext_vector_type(4))) float f32x4;

// ---- workspace layout (bytes). HIGH-WATER 47,102,464 B (< proven 55.1MB).
// psum / perm / aggb share one region: lifetimes strictly disjoint
// (psum: scan1->scan3; perm: fill->fill2; aggb: agg->upd).
#define O_RAW   0L          // float[E] 3.2MB
#define O_DEG   3200000L    // int[N]
#define O_OFF   3400704L    // int[N+1]
#define O_CUR   3601408L    // int[N]
#define O_CSR   3802112L    // uint[E]  packed src|dst<<16 (ids < 2^16)
#define O_EFC   7002112L    // bf16[E*16]  CSR-ordered edge features
#define O_XB    32602112L   // bf16[N*64]
#define O_XSB   39002112L   // bf16[N*16]
#define O_W1B   40602112L   // bf16[144*176]
#define O_UW1B  40653312L   // bf16[128*128]
#define O_UW2B  40686080L   // bf16[64*128]
#define O_AGGB  40702464L   // bf16[N*64] 6.4MB
#define O_PSUM  O_AGGB      // int[98]
#define O_PERM  O_AGGB      // int[E] 3.2MB

__device__ __forceinline__ bf16x8 bzero8() {
    bf16x8 z;
#pragma unroll
    for (int i = 0; i < 8; ++i) z[i] = (__bf16)0.0f;
    return z;
}

// ---- fused: degree count (blocks 0..DEG_B) + fp32->bf16 convert (no ef)
__global__ __launch_bounds__(256) void k_prep(
    const int* __restrict__ ei,
    const float* __restrict__ x, const float* __restrict__ xs,
    const float* __restrict__ w1,
    const float* __restrict__ uw1, const float* __restrict__ uw2,
    int* __restrict__ deg,
    __bf16* __restrict__ xb, __bf16* __restrict__ xsb,
    __bf16* __restrict__ w1b,
    __bf16* __restrict__ uw1b, __bf16* __restrict__ uw2b)
{
    int bid = blockIdx.x;
    if (bid < DEG_B) {
        int e = bid * 256 + threadIdx.x;
        if (e < E_C) atomicAdd(&deg[ei[E_C + e]], 1);
        return;
    }
    long g = (long)(bid - DEG_B) * 256 + threadIdx.x;  // one group = 8 floats
    const long G_X = 400000, G_XS = 500000, G_W1 = 503168,
               G_UW1 = 505216, G_UW2 = 506240;
    if (g >= G_UW2) return;
    const float* src; __bf16* dst; long off;
    if (g < G_X)        { src = x;   dst = xb;   off = g * 8; }
    else if (g < G_XS)  { src = xs;  dst = xsb;  off = (g - G_X) * 8; }
    else if (g < G_W1)  { src = w1;  dst = w1b;  off = (g - G_XS) * 8; }
    else if (g < G_UW1) { src = uw1; dst = uw1b; off = (g - G_W1) * 8; }
    else                { src = uw2; dst = uw2b; off = (g - G_UW1) * 8; }
    float4 a = *(const float4*)(src + off);
    float4 b = *(const float4*)(src + off + 4);
    bf16x8 o;
    o[0] = (__bf16)a.x; o[1] = (__bf16)a.y; o[2] = (__bf16)a.z; o[3] = (__bf16)a.w;
    o[4] = (__bf16)b.x; o[5] = (__bf16)b.y; o[6] = (__bf16)b.z; o[7] = (__bf16)b.w;
    *(bf16x8*)(dst + off) = o;
}

// ---- scan phase 1: per-512-node partial sums
__global__ __launch_bounds__(256) void k_scan1(const int* __restrict__ deg,
                                               int* __restrict__ psum) {
    __shared__ int red[256];
    int b = blockIdx.x, t = threadIdx.x;
    int i = b * 512 + t * 2;
    int s = 0;
    if (i < N_NODES_C) s += deg[i];
    if (i + 1 < N_NODES_C) s += deg[i + 1];
    red[t] = s;
    __syncthreads();
#pragma unroll
    for (int off = 128; off > 0; off >>= 1) {
        if (t < off) red[t] += red[t + off];
        __syncthreads();
    }
    if (t == 0) psum[b] = red[0];
}

// ---- scan phase 2+3 fused
__global__ __launch_bounds__(256) void k_scan3(const int* __restrict__ deg,
                                               const int* __restrict__ psum,
                                               int* __restrict__ offsets,
                                               int* __restrict__ cursor) {
    __shared__ int sc[256];
    __shared__ int bo[2];
    int b = blockIdx.x, t = threadIdx.x;
    if (t < 64) {
        int v1 = (t < SCAN_B) ? psum[t] : 0;
        int v2 = (t + 64 < SCAN_B) ? psum[t + 64] : 0;
        int c   = ((t < b) ? v1 : 0) + ((t + 64 < b) ? v2 : 0);
        int tot = v1 + v2;
#pragma unroll
        for (int off = 32; off > 0; off >>= 1) {
            c   += __shfl_xor(c, off, 64);
            tot += __shfl_xor(tot, off, 64);
        }
        if (t == 0) { bo[0] = c; bo[1] = tot; }
    }
    int i = b * 512 + t * 2;
    int d0 = (i < N_NODES_C) ? deg[i] : 0;
    int d1 = (i + 1 < N_NODES_C) ? deg[i + 1] : 0;
    int s = d0 + d1;
    sc[t] = s;
    __syncthreads();
#pragma unroll
    for (int off = 1; off < 256; off <<= 1) {
        int val = sc[t];
        int add = (t >= off) ? sc[t - off] : 0;
        __syncthreads();
        sc[t] = val + add;
        __syncthreads();
    }
    int excl = bo[0] + sc[t] - s;
    if (i < N_NODES_C)     { offsets[i]     = excl;      cursor[i]     = excl; }
    if (i + 1 < N_NODES_C) { offsets[i + 1] = excl + d0; cursor[i + 1] = excl + d0; }
    if (b == 0 && t == 0)  offsets[N_NODES_C] = bo[1];
}

// ---- CSR fill phase A: slot assignment only (two 4B scatters)
__global__ __launch_bounds__(256) void k_fill(const int* __restrict__ ei,
                                              int* __restrict__ cursor,
                                              unsigned* __restrict__ csrp,
                                              int* __restrict__ perm) {
    int e = blockIdx.x * blockDim.x + threadIdx.x;
    if (e < E_C) {
        int src  = ei[e];
        int dst  = ei[E_C + e];
        int slot = atomicAdd(&cursor[dst], 1);
        csrp[slot] = (unsigned)src | ((unsigned)dst << 16);
        perm[slot] = e;
    }
}

// ---- CSR fill phase B: slot-coalesced ef permute+convert
__global__ __launch_bounds__(256) void k_fill2(const int* __restrict__ perm,
                                               const float* __restrict__ ef,
                                               __bf16* __restrict__ efc) {
    int s = blockIdx.x * blockDim.x + threadIdx.x;
    if (s < E_C) {
        long e = perm[s];
        const float4* efp = (const float4*)(ef + e * 16);
        float4 f0 = efp[0], f1 = efp[1], f2 = efp[2], f3 = efp[3];
        bf16x8 o0, o1;
        o0[0] = (__bf16)f0.x; o0[1] = (__bf16)f0.y; o0[2] = (__bf16)f0.z; o0[3] = (__bf16)f0.w;
        o0[4] = (__bf16)f1.x; o0[5] = (__bf16)f1.y; o0[6] = (__bf16)f1.z; o0[7] = (__bf16)f1.w;
        o1[0] = (__bf16)f2.x; o1[1] = (__bf16)f2.y; o1[2] = (__bf16)f2.z; o1[3] = (__bf16)f2.w;
        o1[4] = (__bf16)f3.x; o1[5] = (__bf16)f3.y; o1[6] = (__bf16)f3.z; o1[7] = (__bf16)f3.w;
        __bf16* d = efc + (long)s * 16;
        *(bf16x8*)d       = o0;
        *(bf16x8*)(d + 8) = o1;
    }
}

// ---- A-fragment gather: full K=176 (x_src|x_dst|xs_src|xs_dst|ef)
__device__ __forceinline__ void load_afrags(
    int src, int dst, long slot, int quad,
    const __bf16* __restrict__ xb, const __bf16* __restrict__ xsb,
    const __bf16* __restrict__ efc,
    bf16x8 a[6])
{
    const __bf16* px = xb + (long)src * 64 + quad * 8;
    const __bf16* pd = xb + (long)dst * 64 + quad * 8;
    a[0] = *(const bf16x8*)(px);
    a[1] = *(const bf16x8*)(px + 32);
    a[2] = *(const bf16x8*)(pd);
    a[3] = *(const bf16x8*)(pd + 32);
    if (quad < 2) {
        a[4] = *(const bf16x8*)(xsb + (long)src * 16 + quad * 8);
        a[5] = *(const bf16x8*)(efc + slot * 16 + quad * 8);
    } else {
        a[4] = *(const bf16x8*)(xsb + (long)dst * 16 + (quad - 2) * 8);
        a[5] = bzero8();
    }
}

// ---- edge attention MLP: r12 CHAMPION, byte-identical. 2-pair ILP,
// 2-slot in-place depth-2 pipeline (copy-free). 72.6us, VGPR 256, no
// spill. Occupancy axis closed (r0-r11); depth-3 needs +48 regs (spill,
// r6). DO NOT add launch_bounds min-waves or touch the loop structure.
__global__ __launch_bounds__(256) void k_scores_mfma(
    const __bf16* __restrict__ xb, const __bf16* __restrict__ xsb,
    const __bf16* __restrict__ efc, const __bf16* __restrict__ w1b,
    const unsigned* __restrict__ csrp,
    const float* __restrict__ b1, const float* __restrict__ w2,
    const float* __restrict__ b2, float* __restrict__ raw)
{
    __shared__ __bf16 w1s[144 * 184];   // 52,992 B
    int tid  = threadIdx.x;
    int lane = tid & 63;

    for (int c = tid; c < 144 * 22; c += 256) {
        int n = c / 22, kk = (c % 22) * 8;
        *(bf16x8*)&w1s[n * 184 + kk] = *(const bf16x8*)(w1b + (long)n * ATT_IN_C + kk);
    }
    for (int n = tid; n < 144; n += 256)
        *(bf16x8*)&w1s[n * 184 + 176] = bzero8();
    __syncthreads();

    int w = blockIdx.x * 4 + (tid >> 6);      // global wave 0..1023
    const int NP = E_C / 32;                  // 25000 edge-pairs
    int per = (NP + 1023) / 1024;             // 25
    long j0 = (long)w * per;
    long j1 = j0 + per; if (j1 > NP) j1 = NP;
    if (j0 >= j1) return;

    int mrow = lane & 15;
    int quad = lane >> 4;
    const __bf16* wls = &w1s[mrow * 184 + quad * 8];

    float b1v[9], w2v[9];
#pragma unroll
    for (int nt = 0; nt < 9; ++nt) {
        int n = nt * 16 + mrow;
        b1v[nt] = b1[n];
        w2v[nt] = w2[n];
    }
    float b2v = b2[0];

    bf16x8 A0[6], B0[6], A1[6], B1[6];
    {
        unsigned e0 = csrp[j0 * 32 + mrow];
        unsigned e1 = csrp[j0 * 32 + 16 + mrow];
        load_afrags((int)(e0 & 0xFFFFu), (int)(e0 >> 16), j0 * 32 + mrow,
                    quad, xb, xsb, efc, A0);
        load_afrags((int)(e1 & 0xFFFFu), (int)(e1 >> 16), j0 * 32 + 16 + mrow,
                    quad, xb, xsb, efc, B0);
        if (j0 + 1 < j1) {
            unsigned f0 = csrp[(j0 + 1) * 32 + mrow];
            unsigned f1 = csrp[(j0 + 1) * 32 + 16 + mrow];
            load_afrags((int)(f0 & 0xFFFFu), (int)(f0 >> 16), (j0 + 1) * 32 + mrow,
                        quad, xb, xsb, efc, A1);
            load_afrags((int)(f1 & 0xFFFFu), (int)(f1 >> 16), (j0 + 1) * 32 + 16 + mrow,
                        quad, xb, xsb, efc, B1);
        }
    }

    auto body = [&](long j, bf16x8 (&FA)[6], bf16x8 (&FB)[6]) {
        unsigned u0 = 0, u1 = 0;
        bool rl = (j + 2 < j1);
        if (rl) {
            u0 = csrp[(j + 2) * 32 + mrow];
            u1 = csrp[(j + 2) * 32 + 16 + mrow];
        }

        f32x4 accA[9], accB[9];
#pragma unroll
        for (int nt = 0; nt < 9; ++nt) {
            accA[nt] = (f32x4){0.f, 0.f, 0.f, 0.f};
            accB[nt] = (f32x4){0.f, 0.f, 0.f, 0.f};
        }
#pragma unroll
        for (int ks = 0; ks < 6; ++ks) {
#pragma unroll
            for (int nt = 0; nt < 9; ++nt) {
                bf16x8 bf = *(const bf16x8*)(wls + nt * (16 * 184) + ks * 32);
                accA[nt] = __builtin_amdgcn_mfma_f32_16x16x32_bf16(
                    FA[ks], bf, accA[nt], 0, 0, 0);
                accB[nt] = __builtin_amdgcn_mfma_f32_16x16x32_bf16(
                    FB[ks], bf, accB[nt], 0, 0, 0);
            }
        }

        if (rl) {
            load_afrags((int)(u0 & 0xFFFFu), (int)(u0 >> 16), (j + 2) * 32 + mrow,
                        quad, xb, xsb, efc, FA);
            load_afrags((int)(u1 & 0xFFFFu), (int)(u1 >> 16), (j + 2) * 32 + 16 + mrow,
                        quad, xb, xsb, efc, FB);
        }

        float pA0 = 0.f, pA1 = 0.f, pA2 = 0.f, pA3 = 0.f;
        float pB0 = 0.f, pB1 = 0.f, pB2 = 0.f, pB3 = 0.f;
#pragma unroll
        for (int nt = 0; nt < 9; ++nt) {
            pA0 += w2v[nt] * fmaxf(accA[nt][0] + b1v[nt], 0.f);
            pA1 += w2v[nt] * fmaxf(accA[nt][1] + b1v[nt], 0.f);
            pA2 += w2v[nt] * fmaxf(accA[nt][2] + b1v[nt], 0.f);
            pA3 += w2v[nt] * fmaxf(accA[nt][3] + b1v[nt], 0.f);
            pB0 += w2v[nt] * fmaxf(accB[nt][0] + b1v[nt], 0.f);
            pB1 += w2v[nt] * fmaxf(accB[nt][1] + b1v[nt], 0.f);
            pB2 += w2v[nt] * fmaxf(accB[nt][2] + b1v[nt], 0.f);
            pB3 += w2v[nt] * fmaxf(accB[nt][3] + b1v[nt], 0.f);
        }
#pragma unroll
        for (int off = 1; off < 16; off <<= 1) {
            pA0 += __shfl_xor(pA0, off, 64);
            pA1 += __shfl_xor(pA1, off, 64);
            pA2 += __shfl_xor(pA2, off, 64);
            pA3 += __shfl_xor(pA3, off, 64);
            pB0 += __shfl_xor(pB0, off, 64);
            pB1 += __shfl_xor(pB1, off, 64);
            pB2 += __shfl_xor(pB2, off, 64);
            pB3 += __shfl_xor(pB3, off, 64);
        }
        if (mrow < 4) {
            float vA = (mrow == 0) ? pA0 : (mrow == 1) ? pA1 : (mrow == 2) ? pA2 : pA3;
            float vB = (mrow == 0) ? pB0 : (mrow == 1) ? pB1 : (mrow == 2) ? pB2 : pB3;
            vA += b2v; vB += b2v;
            vA = (vA >= 0.f) ? vA : 0.01f * vA;
            vB = (vB >= 0.f) ? vB : 0.01f * vB;
            raw[(j * 2) * 16 + quad * 4 + mrow]     = vA;
            raw[(j * 2 + 1) * 16 + quad * 4 + mrow] = vB;
        }
    };

    long j = j0;
    for (; j + 1 < j1; j += 2) {
        body(j,     A0, B0);
        body(j + 1, A1, B1);
    }
    if (j < j1) body(j, A0, B0);
}

// ---- per-node segment softmax + weighted gather -> bf16 agg.
// One wave per node (50000 waves): r13 lesson — fusing this into the
// update tile (3125 waves, 16 serial nodes each) cut the wave-level
// parallelism 16x and cost +36us. The latency-bound random gather NEEDS
// this parallelism; the 12.8MB aggb round-trip it saves is only ~2us.
__global__ __launch_bounds__(256) void k_agg(
    const __bf16* __restrict__ xb, const int* __restrict__ offsets,
    const unsigned* __restrict__ csrp,
    const float* __restrict__ raw, __bf16* __restrict__ aggb)
{
    int tid = threadIdx.x;
    int wave = tid >> 6, lane = tid & 63;
    int v = blockIdx.x * 4 + wave;
    if (v >= N_NODES_C) return;
    int s0 = offsets[v], s1 = offsets[v + 1];

    float m = -INFINITY;
    for (int p = s0 + lane; p < s1; p += 64) m = fmaxf(m, raw[p]);
#pragma unroll
    for (int off = 32; off > 0; off >>= 1) m = fmaxf(m, __shfl_xor(m, off, 64));

    float acc = 0.f, sum = 0.f;
    int p = s0;
    for (; p + 4 <= s1; p += 4) {
        unsigned c0 = csrp[p], c1 = csrp[p + 1], c2 = csrp[p + 2], c3 = csrp[p + 3];
        float r0 = raw[p], r1 = raw[p + 1], r2 = raw[p + 2], r3 = raw[p + 3];
        float v0 = (float)xb[(long)(c0 & 0xFFFFu) * 64 + lane];
        float v1 = (float)xb[(long)(c1 & 0xFFFFu) * 64 + lane];
        float v2 = (float)xb[(long)(c2 & 0xFFFFu) * 64 + lane];
        float v3 = (float)xb[(long)(c3 & 0xFFFFu) * 64 + lane];
        float w0 = expf(r0 - m), w1 = expf(r1 - m);
        float w2 = expf(r2 - m), w3 = expf(r3 - m);
        sum += (w0 + w1) + (w2 + w3);
        acc += w0 * v0 + w1 * v1 + w2 * v2 + w3 * v3;
    }
    for (; p < s1; ++p) {
        int src = (int)(csrp[p] & 0xFFFFu);
        float w = expf(raw[p] - m);
        sum += w;
        acc += w * (float)xb[(long)src * 64 + lane];
    }
    aggb[(long)v * 64 + lane] = (__bf16)(acc / (sum + 1e-9f));
}

// ---- node update MLP via bf16 MFMA: one wave = 16 nodes
__global__ __launch_bounds__(256) void k_upd_mfma(
    const __bf16* __restrict__ xb, const __bf16* __restrict__ aggb,
    const __bf16* __restrict__ w1b, const float* __restrict__ b1,
    const __bf16* __restrict__ w2b, const float* __restrict__ b2,
    float* __restrict__ out)
{
    __shared__ __bf16 ubuf[4][16 * 136];
    int tid = threadIdx.x, wid = tid >> 6, lane = tid & 63;
    int tile = blockIdx.x * 4 + wid;
    if (tile >= UPD_TILES) return;
    int mrow = lane & 15, quad = lane >> 4;

    long node = (long)tile * 16 + mrow;
    bf16x8 a1[4];
    a1[0] = *(const bf16x8*)(xb + node * 64 + quad * 8);
    a1[1] = *(const bf16x8*)(xb + node * 64 + 32 + quad * 8);
    a1[2] = *(const bf16x8*)(aggb + node * 64 + quad * 8);
    a1[3] = *(const bf16x8*)(aggb + node * 64 + 32 + quad * 8);

    bf16x8 b1f[4][8];
#pragma unroll
    for (int ks = 0; ks < 4; ++ks)
#pragma unroll
        for (int nt = 0; nt < 8; ++nt)
            b1f[ks][nt] = *(const bf16x8*)(w1b + (long)(nt * 16 + mrow) * 128 + ks * 32 + quad * 8);

    f32x4 acc1[8];
#pragma unroll
    for (int nt = 0; nt < 8; ++nt) acc1[nt] = (f32x4){0.f, 0.f, 0.f, 0.f};
#pragma unroll
    for (int ks = 0; ks < 4; ++ks)
#pragma unroll
        for (int nt = 0; nt < 8; ++nt)
            acc1[nt] = __builtin_amdgcn_mfma_f32_16x16x32_bf16(a1[ks], b1f[ks][nt], acc1[nt], 0, 0, 0);

    __bf16* ub = ubuf[wid];
#pragma unroll
    for (int nt = 0; nt < 8; ++nt) {
        float bb = b1[nt * 16 + mrow];
#pragma unroll
        for (int r = 0; r < 4; ++r) {
            float h = fmaxf(acc1[nt][r] + bb, 0.f);
            ub[(quad * 4 + r) * 136 + nt * 16 + mrow] = (__bf16)h;
        }
    }

    bf16x8 a2[4];
#pragma unroll
    for (int ks = 0; ks < 4; ++ks)
        a2[ks] = *(bf16x8*)&ub[mrow * 136 + ks * 32 + quad * 8];

    bf16x8 b2f[4][4];
#pragma unroll
    for (int ks = 0; ks < 4; ++ks)
#pragma unroll
        for (int nt = 0; nt < 4; ++nt)
            b2f[ks][nt] = *(const bf16x8*)(w2b + (long)(nt * 16 + mrow) * 128 + ks * 32 + quad * 8);

    f32x4 acc2[4];
#pragma unroll
    for (int nt = 0; nt < 4; ++nt) acc2[nt] = (f32x4){0.f, 0.f, 0.f, 0.f};
#pragma unroll
    for (int ks = 0; ks < 4; ++ks)
#pragma unroll
        for (int nt = 0; nt < 4; ++nt)
            acc2[nt] = __builtin_amdgcn_mfma_f32_16x16x32_bf16(a2[ks], b2f[ks][nt], acc2[nt], 0, 0, 0);

#pragma unroll
    for (int nt = 0; nt < 4; ++nt) {
        float bb = b2[nt * 16 + mrow];
#pragma unroll
        for (int r = 0; r < 4; ++r) {
            long nodeo = (long)tile * 16 + quad * 4 + r;
            out[nodeo * 64 + nt * 16 + mrow] = fmaxf(acc2[nt][r] + bb, 0.f);
        }
    }
}

extern "C" void kernel_launch(void* const* d_in, const int* in_sizes, int n_in,
                              void* d_out, int out_size, void* d_ws, size_t ws_size,
                              hipStream_t stream) {
    const float* x    = (const float*)d_in[0];
    const float* xs   = (const float*)d_in[1];
    const int*   ei   = (const int*)d_in[2];
    const float* ef   = (const float*)d_in[3];
    const float* aw1  = (const float*)d_in[4];
    const float* ab1  = (const float*)d_in[5];
    const float* aw2  = (const float*)d_in[6];
    const float* ab2  = (const float*)d_in[7];
    const float* uw1  = (const float*)d_in[8];
    const float* ub1  = (const float*)d_in[9];
    const float* uw2  = (const float*)d_in[10];
    const float* ub2  = (const float*)d_in[11];
    float* out = (float*)d_out;

    char* ws = (char*)d_ws;
    float*     raw     = (float*)(ws + O_RAW);
    int*       deg     = (int*)(ws + O_DEG);
    int*       offsets = (int*)(ws + O_OFF);
    int*       cursor  = (int*)(ws + O_CUR);
    unsigned*  csrp    = (unsigned*)(ws + O_CSR);
    __bf16*    efc     = (__bf16*)(ws + O_EFC);
    __bf16*    xb      = (__bf16*)(ws + O_XB);
    __bf16*    xsb     = (__bf16*)(ws + O_XSB);
    __bf16*    w1b     = (__bf16*)(ws + O_W1B);
    __bf16*    uw1b    = (__bf16*)(ws + O_UW1B);
    __bf16*    uw2b    = (__bf16*)(ws + O_UW2B);
    __bf16*    aggb    = (__bf16*)(ws + O_AGGB);
    int*       psum    = (int*)(ws + O_PSUM);
    int*       perm    = (int*)(ws + O_PERM);

    hipMemsetAsync(deg, 0, N_NODES_C * sizeof(int), stream);
    hipLaunchKernelGGL(k_prep,     dim3(DEG_B + CVT_B),           dim3(256), 0, stream,
                       ei, x, xs, aw1, uw1, uw2, deg, xb, xsb, w1b, uw1b, uw2b);
    hipLaunchKernelGGL(k_scan1,    dim3(SCAN_B),                  dim3(256), 0, stream, deg, psum);
    hipLaunchKernelGGL(k_scan3,    dim3(SCAN_B),                  dim3(256), 0, stream,
                       deg, psum, offsets, cursor);
    hipLaunchKernelGGL(k_fill,     dim3((E_C + 255) / 256),       dim3(256), 0, stream,
                       ei, cursor, csrp, perm);
    hipLaunchKernelGGL(k_fill2,    dim3((E_C + 255) / 256),       dim3(256), 0, stream,
                       perm, ef, efc);
    hipLaunchKernelGGL(k_scores_mfma, dim3(SCORE_B),              dim3(256), 0, stream,
                       xb, xsb, efc, w1b, csrp, ab1, aw2, ab2, raw);
    hipLaunchKernelGGL(k_agg,      dim3((N_NODES_C + 3) / 4),     dim3(256), 0, stream,
                       xb, offsets, csrp, raw, aggb);
    hipLaunchKernelGGL(k_upd_mfma, dim3((UPD_TILES + 3) / 4),     dim3(256), 0, stream,
                       xb, aggb, uw1b, ub1, uw2b, ub2, out);
}

// Round 15
// 333.505 us; speedup vs baseline: 1.1267x; 1.0494x over previous
//
#include <hip/hip_runtime.h>
#include <math.h>

#define N_NODES_C 50000
#define E_C       800000
#define ATT_IN_C  176
#define ATT_HID_C 144
#define SCAN_B    98      // ceil(50000 / 512)
#define UPD_TILES 3125    // 50000 / 16 exact
#define DEG_B     3125    // 800000 / 256 exact
#define CVT_B     1978    // ceil(506240 / 256)
#define SCORE_B   256     // 1 wave/SIMD: the ONLY non-spill regime (r0-r12 ledger)

typedef __attribute__((ext_vector_type(8))) __bf16 bf16x8;
typedef __attribute__((ext_vector_type(4))) float f32x4;

// ---- workspace layout (bytes). HIGH-WATER 47,102,464 B (< proven 55.1MB).
// This is the r12 CHAMPION configuration (339.6us), restored verbatim:
//   - fused k_fill (slot scatter + ef convert): r14 measured the split
//     version at +10us (extra launch + perm round-trip). Keep fused.
//   - separate k_agg / k_upd: r13 measured the fused version at +36us
//     (16x less wave parallelism on the latency-bound gather). Keep split.
#define O_RAW   0L          // float[E] 3.2MB
#define O_DEG   3200000L    // int[N]
#define O_OFF   3400704L    // int[N+1]
#define O_CUR   3601408L    // int[N]
#define O_CSR   3802112L    // uint[E]  packed src|dst<<16 (ids < 2^16)
#define O_EFC   7002112L    // bf16[E*16]  CSR-ordered edge features
#define O_XB    32602112L   // bf16[N*64]
#define O_XSB   39002112L   // bf16[N*16]
#define O_W1B   40602112L   // bf16[144*176]
#define O_UW1B  40653312L   // bf16[128*128]
#define O_UW2B  40686080L   // bf16[64*128]
#define O_AGGB  40702464L   // bf16[N*64]; psum int[98] overlaps (dead by k_agg)
#define O_PSUM  O_AGGB

__device__ __forceinline__ bf16x8 bzero8() {
    bf16x8 z;
#pragma unroll
    for (int i = 0; i < 8; ++i) z[i] = (__bf16)0.0f;
    return z;
}

// ---- fused: degree count (blocks 0..DEG_B) + fp32->bf16 convert (no ef)
__global__ __launch_bounds__(256) void k_prep(
    const int* __restrict__ ei,
    const float* __restrict__ x, const float* __restrict__ xs,
    const float* __restrict__ w1,
    const float* __restrict__ uw1, const float* __restrict__ uw2,
    int* __restrict__ deg,
    __bf16* __restrict__ xb, __bf16* __restrict__ xsb,
    __bf16* __restrict__ w1b,
    __bf16* __restrict__ uw1b, __bf16* __restrict__ uw2b)
{
    int bid = blockIdx.x;
    if (bid < DEG_B) {
        int e = bid * 256 + threadIdx.x;
        if (e < E_C) atomicAdd(&deg[ei[E_C + e]], 1);
        return;
    }
    long g = (long)(bid - DEG_B) * 256 + threadIdx.x;  // one group = 8 floats
    const long G_X = 400000, G_XS = 500000, G_W1 = 503168,
               G_UW1 = 505216, G_UW2 = 506240;
    if (g >= G_UW2) return;
    const float* src; __bf16* dst; long off;
    if (g < G_X)        { src = x;   dst = xb;   off = g * 8; }
    else if (g < G_XS)  { src = xs;  dst = xsb;  off = (g - G_X) * 8; }
    else if (g < G_W1)  { src = w1;  dst = w1b;  off = (g - G_XS) * 8; }
    else if (g < G_UW1) { src = uw1; dst = uw1b; off = (g - G_W1) * 8; }
    else                { src = uw2; dst = uw2b; off = (g - G_UW1) * 8; }
    float4 a = *(const float4*)(src + off);
    float4 b = *(const float4*)(src + off + 4);
    bf16x8 o;
    o[0] = (__bf16)a.x; o[1] = (__bf16)a.y; o[2] = (__bf16)a.z; o[3] = (__bf16)a.w;
    o[4] = (__bf16)b.x; o[5] = (__bf16)b.y; o[6] = (__bf16)b.z; o[7] = (__bf16)b.w;
    *(bf16x8*)(dst + off) = o;
}

// ---- scan phase 1: per-512-node partial sums
__global__ __launch_bounds__(256) void k_scan1(const int* __restrict__ deg,
                                               int* __restrict__ psum) {
    __shared__ int red[256];
    int b = blockIdx.x, t = threadIdx.x;
    int i = b * 512 + t * 2;
    int s = 0;
    if (i < N_NODES_C) s += deg[i];
    if (i + 1 < N_NODES_C) s += deg[i + 1];
    red[t] = s;
    __syncthreads();
#pragma unroll
    for (int off = 128; off > 0; off >>= 1) {
        if (t < off) red[t] += red[t + off];
        __syncthreads();
    }
    if (t == 0) psum[b] = red[0];
}

// ---- scan phase 2+3 fused
__global__ __launch_bounds__(256) void k_scan3(const int* __restrict__ deg,
                                               const int* __restrict__ psum,
                                               int* __restrict__ offsets,
                                               int* __restrict__ cursor) {
    __shared__ int sc[256];
    __shared__ int bo[2];
    int b = blockIdx.x, t = threadIdx.x;
    if (t < 64) {
        int v1 = (t < SCAN_B) ? psum[t] : 0;
        int v2 = (t + 64 < SCAN_B) ? psum[t + 64] : 0;
        int c   = ((t < b) ? v1 : 0) + ((t + 64 < b) ? v2 : 0);
        int tot = v1 + v2;
#pragma unroll
        for (int off = 32; off > 0; off >>= 1) {
            c   += __shfl_xor(c, off, 64);
            tot += __shfl_xor(tot, off, 64);
        }
        if (t == 0) { bo[0] = c; bo[1] = tot; }
    }
    int i = b * 512 + t * 2;
    int d0 = (i < N_NODES_C) ? deg[i] : 0;
    int d1 = (i + 1 < N_NODES_C) ? deg[i + 1] : 0;
    int s = d0 + d1;
    sc[t] = s;
    __syncthreads();
#pragma unroll
    for (int off = 1; off < 256; off <<= 1) {
        int val = sc[t];
        int add = (t >= off) ? sc[t - off] : 0;
        __syncthreads();
        sc[t] = val + add;
        __syncthreads();
    }
    int excl = bo[0] + sc[t] - s;
    if (i < N_NODES_C)     { offsets[i]     = excl;      cursor[i]     = excl; }
    if (i + 1 < N_NODES_C) { offsets[i + 1] = excl + d0; cursor[i + 1] = excl + d0; }
    if (b == 0 && t == 0)  offsets[N_NODES_C] = bo[1];
}

// ---- CSR fill + ef permute (bf16, CSR slot order), FUSED (r14 lesson:
// splitting this into slot-assign + perm-gather costs +10us)
__global__ __launch_bounds__(256) void k_fill(const int* __restrict__ ei,
                                              const float* __restrict__ ef,
                                              int* __restrict__ cursor,
                                              unsigned* __restrict__ csrp,
                                              __bf16* __restrict__ efc) {
    int e = blockIdx.x * blockDim.x + threadIdx.x;
    if (e < E_C) {
        int src  = ei[e];
        int dst  = ei[E_C + e];
        int slot = atomicAdd(&cursor[dst], 1);
        csrp[slot] = (unsigned)src | ((unsigned)dst << 16);
        const float4* efp = (const float4*)(ef + (long)e * 16);
        float4 f0 = efp[0], f1 = efp[1], f2 = efp[2], f3 = efp[3];
        bf16x8 o0, o1;
        o0[0] = (__bf16)f0.x; o0[1] = (__bf16)f0.y; o0[2] = (__bf16)f0.z; o0[3] = (__bf16)f0.w;
        o0[4] = (__bf16)f1.x; o0[5] = (__bf16)f1.y; o0[6] = (__bf16)f1.z; o0[7] = (__bf16)f1.w;
        o1[0] = (__bf16)f2.x; o1[1] = (__bf16)f2.y; o1[2] = (__bf16)f2.z; o1[3] = (__bf16)f2.w;
        o1[4] = (__bf16)f3.x; o1[5] = (__bf16)f3.y; o1[6] = (__bf16)f3.z; o1[7] = (__bf16)f3.w;
        __bf16* d = efc + (long)slot * 16;
        *(bf16x8*)d       = o0;
        *(bf16x8*)(d + 8) = o1;
    }
}

// ---- A-fragment gather: full K=176 (x_src|x_dst|xs_src|xs_dst|ef)
__device__ __forceinline__ void load_afrags(
    int src, int dst, long slot, int quad,
    const __bf16* __restrict__ xb, const __bf16* __restrict__ xsb,
    const __bf16* __restrict__ efc,
    bf16x8 a[6])
{
    const __bf16* px = xb + (long)src * 64 + quad * 8;
    const __bf16* pd = xb + (long)dst * 64 + quad * 8;
    a[0] = *(const bf16x8*)(px);
    a[1] = *(const bf16x8*)(px + 32);
    a[2] = *(const bf16x8*)(pd);
    a[3] = *(const bf16x8*)(pd + 32);
    if (quad < 2) {
        a[4] = *(const bf16x8*)(xsb + (long)src * 16 + quad * 8);
        a[5] = *(const bf16x8*)(efc + slot * 16 + quad * 8);
    } else {
        a[4] = *(const bf16x8*)(xsb + (long)dst * 16 + (quad - 2) * 8);
        a[5] = bzero8();
    }
}

// ---- edge attention MLP: r12 CHAMPION, byte-identical. 2-pair ILP,
// 2-slot in-place depth-2 pipeline (copy-free). 72.6us, VGPR 256, no
// spill. Occupancy axis closed (r0-r11); depth-3 needs +48 regs (spill,
// r6). DO NOT add launch_bounds min-waves or touch the loop structure.
__global__ __launch_bounds__(256) void k_scores_mfma(
    const __bf16* __restrict__ xb, const __bf16* __restrict__ xsb,
    const __bf16* __restrict__ efc, const __bf16* __restrict__ w1b,
    const unsigned* __restrict__ csrp,
    const float* __restrict__ b1, const float* __restrict__ w2,
    const float* __restrict__ b2, float* __restrict__ raw)
{
    __shared__ __bf16 w1s[144 * 184];   // 52,992 B
    int tid  = threadIdx.x;
    int lane = tid & 63;

    for (int c = tid; c < 144 * 22; c += 256) {
        int n = c / 22, kk = (c % 22) * 8;
        *(bf16x8*)&w1s[n * 184 + kk] = *(const bf16x8*)(w1b + (long)n * ATT_IN_C + kk);
    }
    for (int n = tid; n < 144; n += 256)
        *(bf16x8*)&w1s[n * 184 + 176] = bzero8();
    __syncthreads();

    int w = blockIdx.x * 4 + (tid >> 6);      // global wave 0..1023
    const int NP = E_C / 32;                  // 25000 edge-pairs
    int per = (NP + 1023) / 1024;             // 25
    long j0 = (long)w * per;
    long j1 = j0 + per; if (j1 > NP) j1 = NP;
    if (j0 >= j1) return;

    int mrow = lane & 15;
    int quad = lane >> 4;
    const __bf16* wls = &w1s[mrow * 184 + quad * 8];

    float b1v[9], w2v[9];
#pragma unroll
    for (int nt = 0; nt < 9; ++nt) {
        int n = nt * 16 + mrow;
        b1v[nt] = b1[n];
        w2v[nt] = w2[n];
    }
    float b2v = b2[0];

    bf16x8 A0[6], B0[6], A1[6], B1[6];
    {
        unsigned e0 = csrp[j0 * 32 + mrow];
        unsigned e1 = csrp[j0 * 32 + 16 + mrow];
        load_afrags((int)(e0 & 0xFFFFu), (int)(e0 >> 16), j0 * 32 + mrow,
                    quad, xb, xsb, efc, A0);
        load_afrags((int)(e1 & 0xFFFFu), (int)(e1 >> 16), j0 * 32 + 16 + mrow,
                    quad, xb, xsb, efc, B0);
        if (j0 + 1 < j1) {
            unsigned f0 = csrp[(j0 + 1) * 32 + mrow];
            unsigned f1 = csrp[(j0 + 1) * 32 + 16 + mrow];
            load_afrags((int)(f0 & 0xFFFFu), (int)(f0 >> 16), (j0 + 1) * 32 + mrow,
                        quad, xb, xsb, efc, A1);
            load_afrags((int)(f1 & 0xFFFFu), (int)(f1 >> 16), (j0 + 1) * 32 + 16 + mrow,
                        quad, xb, xsb, efc, B1);
        }
    }

    auto body = [&](long j, bf16x8 (&FA)[6], bf16x8 (&FB)[6]) {
        unsigned u0 = 0, u1 = 0;
        bool rl = (j + 2 < j1);
        if (rl) {
            u0 = csrp[(j + 2) * 32 + mrow];
            u1 = csrp[(j + 2) * 32 + 16 + mrow];
        }

        f32x4 accA[9], accB[9];
#pragma unroll
        for (int nt = 0; nt < 9; ++nt) {
            accA[nt] = (f32x4){0.f, 0.f, 0.f, 0.f};
            accB[nt] = (f32x4){0.f, 0.f, 0.f, 0.f};
        }
#pragma unroll
        for (int ks = 0; ks < 6; ++ks) {
#pragma unroll
            for (int nt = 0; nt < 9; ++nt) {
                bf16x8 bf = *(const bf16x8*)(wls + nt * (16 * 184) + ks * 32);
                accA[nt] = __builtin_amdgcn_mfma_f32_16x16x32_bf16(
                    FA[ks], bf, accA[nt], 0, 0, 0);
                accB[nt] = __builtin_amdgcn_mfma_f32_16x16x32_bf16(
                    FB[ks], bf, accB[nt], 0, 0, 0);
            }
        }

        if (rl) {
            load_afrags((int)(u0 & 0xFFFFu), (int)(u0 >> 16), (j + 2) * 32 + mrow,
                        quad, xb, xsb, efc, FA);
            load_afrags((int)(u1 & 0xFFFFu), (int)(u1 >> 16), (j + 2) * 32 + 16 + mrow,
                        quad, xb, xsb, efc, FB);
        }

        float pA0 = 0.f, pA1 = 0.f, pA2 = 0.f, pA3 = 0.f;
        float pB0 = 0.f, pB1 = 0.f, pB2 = 0.f, pB3 = 0.f;
#pragma unroll
        for (int nt = 0; nt < 9; ++nt) {
            pA0 += w2v[nt] * fmaxf(accA[nt][0] + b1v[nt], 0.f);
            pA1 += w2v[nt] * fmaxf(accA[nt][1] + b1v[nt], 0.f);
            pA2 += w2v[nt] * fmaxf(accA[nt][2] + b1v[nt], 0.f);
            pA3 += w2v[nt] * fmaxf(accA[nt][3] + b1v[nt], 0.f);
            pB0 += w2v[nt] * fmaxf(accB[nt][0] + b1v[nt], 0.f);
            pB1 += w2v[nt] * fmaxf(accB[nt][1] + b1v[nt], 0.f);
            pB2 += w2v[nt] * fmaxf(accB[nt][2] + b1v[nt], 0.f);
            pB3 += w2v[nt] * fmaxf(accB[nt][3] + b1v[nt], 0.f);
        }
#pragma unroll
        for (int off = 1; off < 16; off <<= 1) {
            pA0 += __shfl_xor(pA0, off, 64);
            pA1 += __shfl_xor(pA1, off, 64);
            pA2 += __shfl_xor(pA2, off, 64);
            pA3 += __shfl_xor(pA3, off, 64);
            pB0 += __shfl_xor(pB0, off, 64);
            pB1 += __shfl_xor(pB1, off, 64);
            pB2 += __shfl_xor(pB2, off, 64);
            pB3 += __shfl_xor(pB3, off, 64);
        }
        if (mrow < 4) {
            float vA = (mrow == 0) ? pA0 : (mrow == 1) ? pA1 : (mrow == 2) ? pA2 : pA3;
            float vB = (mrow == 0) ? pB0 : (mrow == 1) ? pB1 : (mrow == 2) ? pB2 : pB3;
            vA += b2v; vB += b2v;
            vA = (vA >= 0.f) ? vA : 0.01f * vA;
            vB = (vB >= 0.f) ? vB : 0.01f * vB;
            raw[(j * 2) * 16 + quad * 4 + mrow]     = vA;
            raw[(j * 2 + 1) * 16 + quad * 4 + mrow] = vB;
        }
    };

    long j = j0;
    for (; j + 1 < j1; j += 2) {
        body(j,     A0, B0);
        body(j + 1, A1, B1);
    }
    if (j < j1) body(j, A0, B0);
}

// ---- per-node segment softmax + weighted gather -> bf16 agg.
// One wave per node (50000 waves): r13 lesson — fusing into the update
// tile (3125 waves) cut wave parallelism 16x and cost +36us.
__global__ __launch_bounds__(256) void k_agg(
    const __bf16* __restrict__ xb, const int* __restrict__ offsets,
    const unsigned* __restrict__ csrp,
    const float* __restrict__ raw, __bf16* __restrict__ aggb)
{
    int tid = threadIdx.x;
    int wave = tid >> 6, lane = tid & 63;
    int v = blockIdx.x * 4 + wave;
    if (v >= N_NODES_C) return;
    int s0 = offsets[v], s1 = offsets[v + 1];

    float m = -INFINITY;
    for (int p = s0 + lane; p < s1; p += 64) m = fmaxf(m, raw[p]);
#pragma unroll
    for (int off = 32; off > 0; off >>= 1) m = fmaxf(m, __shfl_xor(m, off, 64));

    float acc = 0.f, sum = 0.f;
    int p = s0;
    for (; p + 4 <= s1; p += 4) {
        unsigned c0 = csrp[p], c1 = csrp[p + 1], c2 = csrp[p + 2], c3 = csrp[p + 3];
        float r0 = raw[p], r1 = raw[p + 1], r2 = raw[p + 2], r3 = raw[p + 3];
        float v0 = (float)xb[(long)(c0 & 0xFFFFu) * 64 + lane];
        float v1 = (float)xb[(long)(c1 & 0xFFFFu) * 64 + lane];
        float v2 = (float)xb[(long)(c2 & 0xFFFFu) * 64 + lane];
        float v3 = (float)xb[(long)(c3 & 0xFFFFu) * 64 + lane];
        float w0 = expf(r0 - m), w1 = expf(r1 - m);
        float w2 = expf(r2 - m), w3 = expf(r3 - m);
        sum += (w0 + w1) + (w2 + w3);
        acc += w0 * v0 + w1 * v1 + w2 * v2 + w3 * v3;
    }
    for (; p < s1; ++p) {
        int src = (int)(csrp[p] & 0xFFFFu);
        float w = expf(raw[p] - m);
        sum += w;
        acc += w * (float)xb[(long)src * 64 + lane];
    }
    aggb[(long)v * 64 + lane] = (__bf16)(acc / (sum + 1e-9f));
}

// ---- node update MLP via bf16 MFMA: one wave = 16 nodes
__global__ __launch_bounds__(256) void k_upd_mfma(
    const __bf16* __restrict__ xb, const __bf16* __restrict__ aggb,
    const __bf16* __restrict__ w1b, const float* __restrict__ b1,
    const __bf16* __restrict__ w2b, const float* __restrict__ b2,
    float* __restrict__ out)
{
    __shared__ __bf16 ubuf[4][16 * 136];
    int tid = threadIdx.x, wid = tid >> 6, lane = tid & 63;
    int tile = blockIdx.x * 4 + wid;
    if (tile >= UPD_TILES) return;
    int mrow = lane & 15, quad = lane >> 4;

    long node = (long)tile * 16 + mrow;
    bf16x8 a1[4];
    a1[0] = *(const bf16x8*)(xb + node * 64 + quad * 8);
    a1[1] = *(const bf16x8*)(xb + node * 64 + 32 + quad * 8);
    a1[2] = *(const bf16x8*)(aggb + node * 64 + quad * 8);
    a1[3] = *(const bf16x8*)(aggb + node * 64 + 32 + quad * 8);

    bf16x8 b1f[4][8];
#pragma unroll
    for (int ks = 0; ks < 4; ++ks)
#pragma unroll
        for (int nt = 0; nt < 8; ++nt)
            b1f[ks][nt] = *(const bf16x8*)(w1b + (long)(nt * 16 + mrow) * 128 + ks * 32 + quad * 8);

    f32x4 acc1[8];
#pragma unroll
    for (int nt = 0; nt < 8; ++nt) acc1[nt] = (f32x4){0.f, 0.f, 0.f, 0.f};
#pragma unroll
    for (int ks = 0; ks < 4; ++ks)
#pragma unroll
        for (int nt = 0; nt < 8; ++nt)
            acc1[nt] = __builtin_amdgcn_mfma_f32_16x16x32_bf16(a1[ks], b1f[ks][nt], acc1[nt], 0, 0, 0);

    __bf16* ub = ubuf[wid];
#pragma unroll
    for (int nt = 0; nt < 8; ++nt) {
        float bb = b1[nt * 16 + mrow];
#pragma unroll
        for (int r = 0; r < 4; ++r) {
            float h = fmaxf(acc1[nt][r] + bb, 0.f);
            ub[(quad * 4 + r) * 136 + nt * 16 + mrow] = (__bf16)h;
        }
    }

    bf16x8 a2[4];
#pragma unroll
    for (int ks = 0; ks < 4; ++ks)
        a2[ks] = *(bf16x8*)&ub[mrow * 136 + ks * 32 + quad * 8];

    bf16x8 b2f[4][4];
#pragma unroll
    for (int ks = 0; ks < 4; ++ks)
#pragma unroll
        for (int nt = 0; nt < 4; ++nt)
            b2f[ks][nt] = *(const bf16x8*)(w2b + (long)(nt * 16 + mrow) * 128 + ks * 32 + quad * 8);

    f32x4 acc2[4];
#pragma unroll
    for (int nt = 0; nt < 4; ++nt) acc2[nt] = (f32x4){0.f, 0.f, 0.f, 0.f};
#pragma unroll
    for (int ks = 0; ks < 4; ++ks)
#pragma unroll
        for (int nt = 0; nt < 4; ++nt)
            acc2[nt] = __builtin_amdgcn_mfma_f32_16x16x32_bf16(a2[ks], b2f[ks][nt], acc2[nt], 0, 0, 0);

#pragma unroll
    for (int nt = 0; nt < 4; ++nt) {
        float bb = b2[nt * 16 + mrow];
#pragma unroll
        for (int r = 0; r < 4; ++r) {
            long nodeo = (long)tile * 16 + quad * 4 + r;
            out[nodeo * 64 + nt * 16 + mrow] = fmaxf(acc2[nt][r] + bb, 0.f);
        }
    }
}

extern "C" void kernel_launch(void* const* d_in, const int* in_sizes, int n_in,
                              void* d_out, int out_size, void* d_ws, size_t ws_size,
                              hipStream_t stream) {
    const float* x    = (const float*)d_in[0];
    const float* xs   = (const float*)d_in[1];
    const int*   ei   = (const int*)d_in[2];
    const float* ef   = (const float*)d_in[3];
    const float* aw1  = (const float*)d_in[4];
    const float* ab1  = (const float*)d_in[5];
    const float* aw2  = (const float*)d_in[6];
    const float* ab2  = (const float*)d_in[7];
    const float* uw1  = (const float*)d_in[8];
    const float* ub1  = (const float*)d_in[9];
    const float* uw2  = (const float*)d_in[10];
    const float* ub2  = (const float*)d_in[11];
    float* out = (float*)d_out;

    char* ws = (char*)d_ws;
    float*     raw     = (float*)(ws + O_RAW);
    int*       deg     = (int*)(ws + O_DEG);
    int*       offsets = (int*)(ws + O_OFF);
    int*       cursor  = (int*)(ws + O_CUR);
    unsigned*  csrp    = (unsigned*)(ws + O_CSR);
    __bf16*    efc     = (__bf16*)(ws + O_EFC);
    __bf16*    xb      = (__bf16*)(ws + O_XB);
    __bf16*    xsb     = (__bf16*)(ws + O_XSB);
    __bf16*    w1b     = (__bf16*)(ws + O_W1B);
    __bf16*    uw1b    = (__bf16*)(ws + O_UW1B);
    __bf16*    uw2b    = (__bf16*)(ws + O_UW2B);
    __bf16*    aggb    = (__bf16*)(ws + O_AGGB);
    int*       psum    = (int*)(ws + O_PSUM);

    hipMemsetAsync(deg, 0, N_NODES_C * sizeof(int), stream);
    hipLaunchKernelGGL(k_prep,     dim3(DEG_B + CVT_B),           dim3(256), 0, stream,
                       ei, x, xs, aw1, uw1, uw2, deg, xb, xsb, w1b, uw1b, uw2b);
    hipLaunchKernelGGL(k_scan1,    dim3(SCAN_B),                  dim3(256), 0, stream, deg, psum);
    hipLaunchKernelGGL(k_scan3,    dim3(SCAN_B),                  dim3(256), 0, stream,
                       deg, psum, offsets, cursor);
    hipLaunchKernelGGL(k_fill,     dim3((E_C + 255) / 256),       dim3(256), 0, stream,
                       ei, ef, cursor, csrp, efc);
    hipLaunchKernelGGL(k_scores_mfma, dim3(SCORE_B),              dim3(256), 0, stream,
                       xb, xsb, efc, w1b, csrp, ab1, aw2, ab2, raw);
    hipLaunchKernelGGL(k_agg,      dim3((N_NODES_C + 3) / 4),     dim3(256), 0, stream,
                       xb, offsets, csrp, raw, aggb);
    hipLaunchKernelGGL(k_upd_mfma, dim3((UPD_TILES + 3) / 4),     dim3(256), 0, stream,
                       xb, aggb, uw1b, ub1, uw2b, ub2, out);
}